// Round 11
// baseline (796.911 us; speedup 1.0000x reference)
//
#include <hip/hip_runtime.h>
#include <hip/hip_bf16.h>
#include <stdint.h>

typedef __attribute__((ext_vector_type(4))) float f32x4;
typedef __attribute__((ext_vector_type(8))) short short8v;
typedef __attribute__((ext_vector_type(4))) unsigned short u16x4;

constexpr int kT  = 256;
constexpr int kA  = 160;

__device__ __forceinline__ float bf2f(unsigned short u){
  union { unsigned int u; float f; } c; c.u = ((unsigned int)u) << 16; return c.f;
}
__device__ __forceinline__ unsigned short f2bf(float f){
  union { float f; unsigned int u; } c; c.f = f;
  unsigned int r = (c.u + 0x7FFFu + ((c.u >> 16) & 1u)) >> 16;
  return (unsigned short)r;
}
__device__ __forceinline__ float sigmoid_fast(float x){
  return __builtin_amdgcn_rcpf(1.f + __expf(-x));
}
__device__ __forceinline__ float tanhf_fast(float x){
  float xc = fminf(fmaxf(x, -15.f), 15.f);
  float t = __expf(2.f * xc);
  return (t - 1.f) * __builtin_amdgcn_rcpf(t + 1.f);
}
__device__ __forceinline__ void gload_lds16(const void* g, void* l){
  __builtin_amdgcn_global_load_lds((const __attribute__((address_space(1))) void*)g,
                                   (__attribute__((address_space(3))) void*)l, 16, 0, 0);
}
__device__ __forceinline__ void bar_lgkm(){
  asm volatile("s_waitcnt lgkmcnt(0)" ::: "memory");
  __builtin_amdgcn_s_barrier();
  asm volatile("" ::: "memory");
}
__device__ __forceinline__ void bar_only(){
  asm volatile("" ::: "memory");
  __builtin_amdgcn_s_barrier();
  asm volatile("" ::: "memory");
}

// ---------------- diagnostic fill (f32) ----------------
__global__ __launch_bounds__(256) void k_fill_f32(float* out, int n, float v){
  int i = blockIdx.x * blockDim.x + threadIdx.x;
  if (i < n) out[i] = v;
}

// ---------------- f32 -> bf16 convert ----------------
__global__ __launch_bounds__(256) void k_f32_to_bf16(const float* __restrict__ src,
                                                     unsigned short* __restrict__ dst, int n4){
  int stride = gridDim.x * blockDim.x;
  for (int i = blockIdx.x * blockDim.x + threadIdx.x; i < n4; i += stride){
    f32x4 v = *(const f32x4*)(src + (size_t)i * 4);
    u16x4 o;
    o[0] = f2bf(v[0]); o[1] = f2bf(v[1]); o[2] = f2bf(v[2]); o[3] = f2bf(v[3]);
    *(u16x4*)(dst + (size_t)i * 4) = o;
  }
}

// ---------------- gi = shift(act) @ wih^T + bih ----------------
__global__ __launch_bounds__(384) void k_gi(const float* __restrict__ act,
                                            const float* __restrict__ wih,
                                            const float* __restrict__ bih,
                                            float* __restrict__ gi){
  int blk = blockIdx.x;
  int b = blk >> 5, tg = blk & 31;
  int j = threadIdx.x;
  __shared__ __align__(16) float xh[8][kA];
  for (int idx = j; idx < 8 * kA; idx += 384){
    int u = idx / kA, i = idx - u * kA;
    int t = tg * 8 + u;
    xh[u][i] = (t == 0) ? 0.f : act[((size_t)b * kT + t - 1) * kA + i];
  }
  __syncthreads();
  float acc[8] = {0,0,0,0,0,0,0,0};
  for (int i = 0; i < kA; i += 4){
    f32x4 wv = *(const f32x4*)(wih + (size_t)j * kA + i);
#pragma unroll
    for (int jj = 0; jj < 4; ++jj)
#pragma unroll
      for (int u = 0; u < 8; ++u)
        acc[u] += wv[jj] * xh[u][i + jj];
  }
  float bv = bih[j];
#pragma unroll
  for (int u = 0; u < 8; ++u)
    gi[((size_t)b * kT + tg * 8 + u) * 384 + j] = acc[u] + bv;
}

// ================= r10 GEMM body (512 thr, 128x576) — kept for fused GEMM1 =================
template<int RELU>
__device__ __forceinline__ void gemm576_body(const unsigned short* __restrict__ A,
                                             const unsigned short* __restrict__ B,
                                             const float* __restrict__ bias,
                                             unsigned short* __restrict__ C,
                                             int M, int Nc, int K, int ldc,
                                             int bid, int nwg, char* smem){
  int nbm = M >> 7;
  int cpx = nwg >> 3;
  int sw  = (bid & 7) * cpx + (bid >> 3);
  int bm = sw % nbm, bn = sw / nbm;
  int arow0 = bm << 7;
  int bcol0 = bn * 576;
  int t = threadIdx.x;
  int l = t & 63, w = t >> 6;
  int wr = w >> 2, wc = w & 3;
  int lr = l & 15, kq = l >> 4;
  int Kb = K * 2;
  int ar = t >> 2, ap = t & 3;
  size_t aoffg = (size_t)ar * Kb + ((ap ^ ((ar >> 1) & 3)) << 4);
  size_t boffg[5];
#pragma unroll
  for (int i = 0; i < 5; ++i){
    int q = i * 512 + t, r = q >> 2, p = q & 3;
    boffg[i] = (size_t)r * Kb + ((p ^ ((r >> 1) & 3)) << 4);
  }
  const char* Ag = (const char*)(A + (size_t)arow0 * K);
  const char* Bg = (const char*)(B + (size_t)bcol0 * K);
  int dA = t * 16;
  int kk16 = (kq ^ ((lr >> 1) & 3)) << 4;
  int aRd = (wr * 64 + lr) * 64 + kk16;
  int bRd = 8192 + (wc * 144 + lr) * 64 + kk16;
  f32x4 acc[4][9] = {};
  int nt = K >> 5;

  auto stage = [&](int kt, int bi){
    size_t kb = (size_t)kt * 64;
    char* Ld = smem + bi * 49152;
    gload_lds16(Ag + aoffg + kb, Ld + dA);
#pragma unroll
    for (int i = 0; i < 5; ++i)
      gload_lds16(Bg + boffg[i] + kb, Ld + 8192 + i * 8192 + dA);
  };

  stage(0, 0);
  stage(1, 1);
  asm volatile("s_waitcnt vmcnt(6)" ::: "memory");
  int cur = 0;
  for (int kt = 0; kt < nt; ++kt){
    bar_only();
    if (kt + 2 < nt){
      int nb = cur + 2; if (nb >= 3) nb -= 3;
      stage(kt + 2, nb);
    }
    const char* Ld = smem + cur * 49152;
    short8v af[4];
#pragma unroll
    for (int m = 0; m < 4; ++m) af[m] = *(const short8v*)(Ld + aRd + m * 1024);
#pragma unroll
    for (int c = 0; c < 3; ++c){
      short8v bf[3];
#pragma unroll
      for (int j = 0; j < 3; ++j) bf[j] = *(const short8v*)(Ld + bRd + (c * 3 + j) * 1024);
      __builtin_amdgcn_s_setprio(1);
#pragma unroll
      for (int m = 0; m < 4; ++m)
#pragma unroll
        for (int j = 0; j < 3; ++j)
          acc[m][c * 3 + j] = __builtin_amdgcn_mfma_f32_16x16x32_bf16(af[m], bf[j], acc[m][c * 3 + j], 0, 0, 0);
      __builtin_amdgcn_s_setprio(0);
    }
    if (kt + 1 < nt){
      if (kt + 2 < nt) asm volatile("s_waitcnt vmcnt(6)" ::: "memory");
      else             asm volatile("s_waitcnt vmcnt(0)" ::: "memory");
    }
    ++cur; if (cur == 3) cur = 0;
  }

#pragma unroll
  for (int m = 0; m < 4; ++m){
    int row = arow0 + wr * 64 + m * 16 + kq * 4;
#pragma unroll
    for (int n = 0; n < 9; ++n){
      int col = bcol0 + wc * 144 + n * 16 + lr;
      float bv = bias[col];
#pragma unroll
      for (int r = 0; r < 4; ++r){
        float v = acc[m][n][r] + bv;
        if (RELU) v = fmaxf(v, 0.f);
        C[(size_t)(row + r) * ldc + col] = f2bf(v);
      }
    }
  }
}

// ================= NEW GEMM2: 128(M)x288(N), BK=32, 256 thr / 4 waves, 2 blocks/CU =========
// Per-wave 64x144 (acc[4][9], r10-proven). 3 LDS bufs x 26KB = 78KB -> 2 blocks/CU (16 waves).
// Stage 1664 transfers/buf: waves 0,1 carry 7 loads/tile, waves 2,3 carry 6 (wave-uniform
// vmcnt(7)/vmcnt(6)). Depth-2 rotation + counted vmcnt (r10 ledger). Swizzle r7-verified.
template<int RELU>
__global__ __launch_bounds__(256) void k_gemm288(const unsigned short* __restrict__ A,
                                                 const unsigned short* __restrict__ B,
                                                 const float* __restrict__ bias,
                                                 unsigned short* __restrict__ C,
                                                 int M, int Nc, int K, int ldc){
  __shared__ __align__(16) char smem[79872];           // 3 x 26624
  int nbm = M >> 7;
  int nwg = gridDim.x, bid = blockIdx.x;
  int cpx = nwg >> 3;                                  // nwg % 8 == 0
  int sw  = (bid & 7) * cpx + (bid >> 3);              // XCD-aware
  int bm = sw % nbm, bn = sw / nbm;                    // N-major
  int arow0 = bm << 7;
  int bcol0 = bn * 288;
  int t = threadIdx.x;
  int l = t & 63, w = t >> 6;
  int wr = w >> 1, wc = w & 1;                         // wave grid 2M x 2N
  int lr = l & 15, kq = l >> 4;
  int Kb = K * 2;
  // A: 512 transfers (q = t, 256+t). B: 1152 transfers (q = i*256+t, i=0..3; +1024+t for t<128)
  size_t aoffg[2];
#pragma unroll
  for (int i = 0; i < 2; ++i){
    int q = i * 256 + t, r = q >> 2, p = q & 3;
    aoffg[i] = (size_t)r * Kb + ((p ^ ((r >> 1) & 3)) << 4);
  }
  size_t boffg[5];
#pragma unroll
  for (int i = 0; i < 5; ++i){
    int q = i * 256 + t, r = q >> 2, p = q & 3;
    boffg[i] = (size_t)r * Kb + ((p ^ ((r >> 1) & 3)) << 4);
  }
  const char* Ag = (const char*)(A + (size_t)arow0 * K);
  const char* Bg = (const char*)(B + (size_t)bcol0 * K);
  int dT = t * 16;
  int kk16 = (kq ^ ((lr >> 1) & 3)) << 4;
  int aRd = (wr * 64 + lr) * 64 + kk16;
  int bRd = 8192 + (wc * 144 + lr) * 64 + kk16;
  f32x4 acc[4][9] = {};
  int nt = K >> 5;
  bool w01 = (t < 128);                                 // waves 0,1 (wave-uniform)

  auto stage = [&](int kt, int bi){
    size_t kb = (size_t)kt * 64;
    char* Ld = smem + bi * 26624;
    gload_lds16(Ag + aoffg[0] + kb, Ld + dT);
    gload_lds16(Ag + aoffg[1] + kb, Ld + 4096 + dT);
#pragma unroll
    for (int i = 0; i < 4; ++i)
      gload_lds16(Bg + boffg[i] + kb, Ld + 8192 + i * 4096 + dT);
    if (w01) gload_lds16(Bg + boffg[4] + kb, Ld + 24576 + dT);
  };
  auto waitJ = [&](){
    if (w01) asm volatile("s_waitcnt vmcnt(7)" ::: "memory");
    else     asm volatile("s_waitcnt vmcnt(6)" ::: "memory");
  };

  stage(0, 0);
  stage(1, 1);
  waitJ();                                              // tile 0 landed (own wave)
  int cur = 0;
  for (int kt = 0; kt < nt; ++kt){
    bar_only();                                         // all waves: tile kt visible
    if (kt + 2 < nt){
      int nb = cur + 2; if (nb >= 3) nb -= 3;
      stage(kt + 2, nb);
    }
    const char* Ld = smem + cur * 26624;
    short8v af[4];
#pragma unroll
    for (int m = 0; m < 4; ++m) af[m] = *(const short8v*)(Ld + aRd + m * 1024);
#pragma unroll
    for (int c = 0; c < 3; ++c){
      short8v bf[3];
#pragma unroll
      for (int j = 0; j < 3; ++j) bf[j] = *(const short8v*)(Ld + bRd + (c * 3 + j) * 1024);
      __builtin_amdgcn_s_setprio(1);
#pragma unroll
      for (int m = 0; m < 4; ++m)
#pragma unroll
        for (int j = 0; j < 3; ++j)
          acc[m][c * 3 + j] = __builtin_amdgcn_mfma_f32_16x16x32_bf16(af[m], bf[j], acc[m][c * 3 + j], 0, 0, 0);
      __builtin_amdgcn_s_setprio(0);
    }
    if (kt + 1 < nt){
      if (kt + 2 < nt) waitJ();                         // tile kt+1 retired before next bar
      else             asm volatile("s_waitcnt vmcnt(0)" ::: "memory");
    }
    ++cur; if (cur == 3) cur = 0;
  }

#pragma unroll
  for (int m = 0; m < 4; ++m){
    int row = arow0 + wr * 64 + m * 16 + kq * 4;
#pragma unroll
    for (int n = 0; n < 9; ++n){
      int col = bcol0 + wc * 144 + n * 16 + lr;
      float bv = bias[col];
#pragma unroll
      for (int r = 0; r < 4; ++r){
        float v = acc[m][n][r] + bv;
        if (RELU) v = fmaxf(v, 0.f);
        C[(size_t)(row + r) * ldc + col] = f2bf(v);
      }
    }
  }
}

// ---------------- fused: blocks 0-7 GRU; 8-263 GEMM1 (st@w0^T); 264+ convert ----
__global__ __launch_bounds__(512) void k_gru_g1_conv(const float* __restrict__ gi,
                                                     const float* __restrict__ whh,
                                                     const float* __restrict__ bhh,
                                                     float* __restrict__ enc,
                                                     const unsigned short* __restrict__ stb,
                                                     const unsigned short* __restrict__ w0b,
                                                     const float* __restrict__ hb0,
                                                     unsigned short* __restrict__ zb,
                                                     const float* __restrict__ csrc,
                                                     unsigned short* __restrict__ cdst,
                                                     int n4){
  __shared__ __align__(16) char smem[147456];
  int blk = blockIdx.x;
  if (blk >= 264){
    int stride = (gridDim.x - 264) * 512;
    for (int i = (blk - 264) * 512 + threadIdx.x; i < n4; i += stride){
      f32x4 v = *(const f32x4*)(csrc + (size_t)i * 4);
      u16x4 o;
      o[0] = f2bf(v[0]); o[1] = f2bf(v[1]); o[2] = f2bf(v[2]); o[3] = f2bf(v[3]);
      *(u16x4*)(cdst + (size_t)i * 4) = o;
    }
    return;
  }
  if (blk >= 8){
    gemm576_body<1>(stb, w0b, hb0, zb, 2048, 9216, 256, 9216, blk - 8, 256, smem);
    return;
  }
  // ---- GRU ----
  float* h_lds = (float*)smem;
  float (*red)[128] = (float(*)[128])(smem + 512);
  int b = blk;
  int tid = threadIdx.x;
  int e = tid & 127, s = tid >> 7;
  float W0[32], W1[32], W2[32];
#pragma unroll
  for (int k = 0; k < 32; ++k){
    W0[k] = whh[(size_t)(0 * 128 + e) * 128 + s * 32 + k];
    W1[k] = whh[(size_t)(1 * 128 + e) * 128 + s * 32 + k];
    W2[k] = whh[(size_t)(2 * 128 + e) * 128 + s * 32 + k];
  }
  if (tid < 128) h_lds[tid] = 0.f;
  float bh0 = 0.f, bh1 = 0.f, bh2 = 0.f;
  if (tid < 128){ bh0 = bhh[e]; bh1 = bhh[128 + e]; bh2 = bhh[256 + e]; }
  const float* gib = gi + (size_t)b * kT * 384;
  float* encb = enc + (size_t)b * kT * 128;
  float gir = 0.f, giz = 0.f, gin = 0.f;
  if (tid < 128){ gir = gib[e]; giz = gib[128 + e]; gin = gib[256 + e]; }
  bar_lgkm();
  for (int t = 0; t < kT; ++t){
    float p0 = 0.f, p1 = 0.f, p2 = 0.f;
#pragma unroll
    for (int k4 = 0; k4 < 8; ++k4){
      f32x4 hv = *(const f32x4*)(h_lds + s * 32 + k4 * 4);
#pragma unroll
      for (int jj = 0; jj < 4; ++jj){
        p0 += W0[k4 * 4 + jj] * hv[jj];
        p1 += W1[k4 * 4 + jj] * hv[jj];
        p2 += W2[k4 * 4 + jj] * hv[jj];
      }
    }
    float nir = 0.f, niz = 0.f, nin = 0.f;
    if (t + 1 < kT && tid < 128){
      const float* gn = gib + (size_t)(t + 1) * 384;
      nir = gn[e]; niz = gn[128 + e]; nin = gn[256 + e];
    }
    red[s * 3 + 0][e] = p0; red[s * 3 + 1][e] = p1; red[s * 3 + 2][e] = p2;
    bar_lgkm();
    if (tid < 128){
      float ghr = red[0][e] + red[3][e] + red[6][e] + red[9][e]  + bh0;
      float ghz = red[1][e] + red[4][e] + red[7][e] + red[10][e] + bh1;
      float ghn = red[2][e] + red[5][e] + red[8][e] + red[11][e] + bh2;
      float r = sigmoid_fast(gir + ghr);
      float z = sigmoid_fast(giz + ghz);
      float n = tanhf_fast(gin + r * ghn);
      float hnew = (1.f - z) * n + z * h_lds[e];
      h_lds[e] = hnew;
      encb[t * 128 + e] = hnew;
    }
    bar_lgkm();
    gir = nir; giz = niz; gin = nin;
  }
}

// ---------------- s0/ps/pe ----------------
__global__ __launch_bounds__(128) void k_attnpre(const float* __restrict__ enc,
                                                 const float* __restrict__ fc_w,
                                                 const float* __restrict__ fc_b,
                                                 const float* __restrict__ attn_w,
                                                 float* __restrict__ ps,
                                                 float* __restrict__ pe){
  int bt = blockIdx.x, o = threadIdx.x;
  __shared__ __align__(16) float ench[128], s0h[128];
  ench[o] = enc[(size_t)bt * 128 + o];
  __syncthreads();
  float a0 = fc_b[o], a1 = 0.f;
  for (int i = 0; i < 128; i += 4){
    f32x4 wv = *(const f32x4*)(fc_w + (size_t)o * 128 + i);
    f32x4 we = *(const f32x4*)(attn_w + (size_t)o * 256 + 128 + i);
    f32x4 ev = *(const f32x4*)(ench + i);
#pragma unroll
    for (int jj = 0; jj < 4; ++jj){ a0 += wv[jj] * ev[jj]; a1 += we[jj] * ev[jj]; }
  }
  s0h[o] = tanhf_fast(a0);
  pe[(size_t)bt * 128 + o] = a1;
  __syncthreads();
  float a2 = 0.f;
  for (int i = 0; i < 128; i += 4){
    f32x4 ws = *(const f32x4*)(attn_w + (size_t)o * 256 + i);
    f32x4 sv = *(const f32x4*)(s0h + i);
#pragma unroll
    for (int jj = 0; jj < 4; ++jj) a2 += ws[jj] * sv[jj];
  }
  ps[(size_t)bt * 128 + o] = a2;
}

// ---------------- causal additive attention ----------------
__global__ __launch_bounds__(256) void k_attn(const float* __restrict__ enc,
                                              const float* __restrict__ ps,
                                              const float* __restrict__ pe,
                                              const float* __restrict__ v_w,
                                              float* __restrict__ cbuf){
  int q = blockIdx.x, b = blockIdx.y;
  int tid = threadIdx.x;
  __shared__ __align__(16) float psh[128], vwh[128];
  __shared__ __align__(16) float sch[256];
  __shared__ __align__(16) float rr[256];
  __shared__ float mxs, dns;
  if (tid < 128){
    psh[tid] = ps[((size_t)b * kT + q) * 128 + tid];
    vwh[tid] = v_w[tid];
  }
  __syncthreads();
  int nk = q + 1;
  for (int k = tid; k < nk; k += 256){
    const float* per = pe + ((size_t)b * kT + k) * 128;
    float sc = 0.f;
    for (int d = 0; d < 128; d += 4){
      f32x4 pv = *(const f32x4*)(per + d);
      f32x4 qv = *(const f32x4*)(psh + d);
      sc += vwh[d + 0] * tanhf_fast(qv[0] + pv[0]);
      sc += vwh[d + 1] * tanhf_fast(qv[1] + pv[1]);
      sc += vwh[d + 2] * tanhf_fast(qv[2] + pv[2]);
      sc += vwh[d + 3] * tanhf_fast(qv[3] + pv[3]);
    }
    sch[k] = sc;
  }
  __syncthreads();
  float lm = -3.0e38f;
  for (int k = tid; k < nk; k += 256) lm = fmaxf(lm, sch[k]);
  rr[tid] = lm; __syncthreads();
  for (int off = 128; off > 0; off >>= 1){
    if (tid < off) rr[tid] = fmaxf(rr[tid], rr[tid + off]);
    __syncthreads();
  }
  if (tid == 0) mxs = rr[0];
  __syncthreads();
  float mxv = mxs;
  float lsum = 0.f;
  for (int k = tid; k < nk; k += 256){
    float p = __expf(sch[k] - mxv);
    sch[k] = p; lsum += p;
  }
  __syncthreads();
  rr[tid] = lsum; __syncthreads();
  for (int off = 128; off > 0; off >>= 1){
    if (tid < off) rr[tid] += rr[tid + off];
    __syncthreads();
  }
  if (tid == 0) dns = __builtin_amdgcn_rcpf(rr[0]);
  __syncthreads();
  float rd = dns;
  int d = tid & 127, half = tid >> 7;
  float acc = 0.f;
  for (int k = half; k < nk; k += 2)
    acc += sch[k] * enc[((size_t)b * kT + k) * 128 + d];
  rr[tid] = acc; __syncthreads();
  if (half == 0)
    cbuf[((size_t)b * kT + q) * 128 + d] = (acc + rr[d + 128]) * rd;
}

// ---------------- final: heads + per-row 288x32 contraction -> q (f32 out) ----------------
__global__ __launch_bounds__(256) void k_final(const float* __restrict__ states,
                                               const float* __restrict__ act,
                                               const float* __restrict__ cbuf,
                                               const unsigned short* __restrict__ w1f, // bf16
                                               const float* __restrict__ hb1_w, const float* __restrict__ hb1_b,
                                               const float* __restrict__ hwf_w0, const float* __restrict__ hwf_b0,
                                               const float* __restrict__ hwf_w1, const float* __restrict__ hwf_b1,
                                               const float* __restrict__ hb2_w0, const float* __restrict__ hb2_b0,
                                               const float* __restrict__ hb2_w1, const float* __restrict__ hb2_b1,
                                               float* __restrict__ out){
  int bt = blockIdx.x, tid = threadIdx.x;
  __shared__ __align__(16) float sth[256], inph[288], red[256];
  __shared__ __align__(16) float t1h[32], t2h[32], b1h[32], wfh[32], hvals[32];
  __shared__ float b2s;
  sth[tid] = states[(size_t)bt * 256 + tid];
  if (tid < 160) inph[tid] = act[(size_t)bt * 160 + tid];
  if (tid < 128) inph[160 + tid] = cbuf[(size_t)bt * 128 + tid];
  __syncthreads();
  int o = tid & 31, s = tid >> 5;
  float p1 = 0.f, p2 = 0.f, p3 = 0.f;
  for (int k = s * 32; k < s * 32 + 32; k += 4){
    f32x4 sv  = *(const f32x4*)(sth + k);
    f32x4 w1v = *(const f32x4*)(hwf_w0 + (size_t)o * 256 + k);
    f32x4 w2v = *(const f32x4*)(hb2_w0 + (size_t)o * 256 + k);
    f32x4 w3v = *(const f32x4*)(hb1_w  + (size_t)o * 256 + k);
#pragma unroll
    for (int jj = 0; jj < 4; ++jj){
      p1 += w1v[jj] * sv[jj]; p2 += w2v[jj] * sv[jj]; p3 += w3v[jj] * sv[jj];
    }
  }
  red[tid] = p1; __syncthreads();
  if (tid < 32){
    float a = hwf_b0[tid];
#pragma unroll
    for (int s8 = 0; s8 < 8; ++s8) a += red[s8 * 32 + tid];
    t1h[tid] = fmaxf(a, 0.f);
  }
  __syncthreads();
  red[tid] = p2; __syncthreads();
  if (tid < 32){
    float a = hb2_b0[tid];
#pragma unroll
    for (int s8 = 0; s8 < 8; ++s8) a += red[s8 * 32 + tid];
    t2h[tid] = fmaxf(a, 0.f);
  }
  __syncthreads();
  red[tid] = p3; __syncthreads();
  if (tid < 32){
    float a = hb1_b[tid];
#pragma unroll
    for (int s8 = 0; s8 < 8; ++s8) a += red[s8 * 32 + tid];
    b1h[tid] = a;
  }
  __syncthreads();
  if (tid < 32){
    float a = hwf_b1[tid];
#pragma unroll
    for (int j = 0; j < 32; ++j) a += hwf_w1[(size_t)tid * 32 + j] * t1h[j];
    wfh[tid] = a;
  }
  if (tid == 64){
    float a = hb2_b1[0];
#pragma unroll
    for (int j = 0; j < 32; ++j) a += hb2_w1[j] * t2h[j];
    b2s = a;
  }
  __syncthreads();
  float ph = 0.f;
  const unsigned short* wrow = w1f + (size_t)bt * 9216;
  for (int i = s * 36; i < s * 36 + 36; ++i)
    ph += inph[i] * bf2f(wrow[i * 32 + o]);
  red[tid] = ph; __syncthreads();
  if (tid < 32){
    float a = b1h[tid];
#pragma unroll
    for (int s8 = 0; s8 < 8; ++s8) a += red[s8 * 32 + tid];
    hvals[tid] = fmaxf(a, 0.f) * wfh[tid];
  }
  __syncthreads();
  if (tid == 0){
    float q = b2s;
#pragma unroll
    for (int j = 0; j < 32; ++j) q += hvals[j];
    out[bt] = q;
  }
}

extern "C" void kernel_launch(void* const* d_in, const int* in_sizes, int n_in,
                              void* d_out, int out_size, void* d_ws, size_t ws_size,
                              hipStream_t stream){
  float* outp = (float*)d_out;

  bool ok = (n_in == 24) && out_size == 2048 &&
            in_sizes[0] == 327680 && in_sizes[1] == 524288 &&
            in_sizes[2] == 61440  && in_sizes[3] == 49152 &&
            in_sizes[10] == 2359296 && in_sizes[12] == 84934656;
  if (!ok){
    k_fill_f32<<<dim3(8), dim3(256), 0, stream>>>(outp, 2048, 1.0e6f);
    return;
  }

  const float* act    = (const float*)d_in[0];
  const float* states = (const float*)d_in[1];
  const float* wih    = (const float*)d_in[2];
  const float* whh    = (const float*)d_in[3];
  const float* bih    = (const float*)d_in[4];
  const float* bhh    = (const float*)d_in[5];
  const float* fc_w   = (const float*)d_in[6];
  const float* fc_b   = (const float*)d_in[7];
  const float* attn_w = (const float*)d_in[8];
  const float* v_w    = (const float*)d_in[9];
  const float* hw1_w0 = (const float*)d_in[10];
  const float* hw1_b0 = (const float*)d_in[11];
  const float* hw1_w1 = (const float*)d_in[12];
  const float* hw1_b1 = (const float*)d_in[13];
  const float* hwf_w0 = (const float*)d_in[14];
  const float* hwf_b0 = (const float*)d_in[15];
  const float* hwf_w1 = (const float*)d_in[16];
  const float* hwf_b1 = (const float*)d_in[17];
  const float* hb1_w  = (const float*)d_in[18];
  const float* hb1_b  = (const float*)d_in[19];
  const float* hb2_w0 = (const float*)d_in[20];
  const float* hb2_b0 = (const float*)d_in[21];
  const float* hb2_w1 = (const float*)d_in[22];
  const float* hb2_b1 = (const float*)d_in[23];

  char* ws = (char*)d_ws;
  size_t off = 0;
  auto alloc = [&](size_t bytes)->void*{
    void* p = ws + off; off += (bytes + 255) & ~(size_t)255; return p;
  };
  unsigned short* zb  = (unsigned short*)alloc((size_t)2048 * 9216 * 2);
  unsigned short* w1f = (unsigned short*)alloc((size_t)2048 * 9216 * 2);
  unsigned short* w0b = (unsigned short*)alloc((size_t)9216 * 256 * 2);
  unsigned short* stb = (unsigned short*)alloc((size_t)2048 * 256 * 2);
  float* gi   = (float*)alloc((size_t)2048 * 384 * 4);
  float* enc  = (float*)alloc((size_t)2048 * 128 * 4);
  float* psb  = (float*)alloc((size_t)2048 * 128 * 4);
  float* peb  = (float*)alloc((size_t)2048 * 128 * 4);
  float* cbuf = (float*)alloc((size_t)2048 * 128 * 4);
  size_t floor_bytes = off;
  const size_t row_bytes = (size_t)9216 * 2;
  const size_t slack = (size_t)2 << 20;
  if (ws_size < floor_bytes + 288 * row_bytes + slack){
    k_fill_f32<<<dim3(8), dim3(256), 0, stream>>>(outp, 2048, (float)(ws_size >> 20));
    return;
  }
  size_t avail = ws_size - floor_bytes - slack;
  int chunk_rows = (int)(((avail / row_bytes) / 288) * 288);
  if (chunk_rows > 9216) chunk_rows = 9216;
  unsigned short* w1c = (unsigned short*)(ws + floor_bytes);
  int first_nc = chunk_rows;

  // ---- pipeline ----
  k_f32_to_bf16<<<dim3(1024), dim3(256), 0, stream>>>(hw1_w0, w0b, 9216 * 256 / 4);
  k_f32_to_bf16<<<dim3(256),  dim3(256), 0, stream>>>(states, stb, 2048 * 256 / 4);
  k_gi<<<dim3(256), dim3(384), 0, stream>>>(act, wih, bih, gi);
  // GRU (0-7) || GEMM1 z=relu(st@w0^T+b0) (8-263) || convert w1 chunk0 (264+)
  k_gru_g1_conv<<<dim3(768), dim3(512), 0, stream>>>(gi, whh, bhh, enc,
                                                     stb, w0b, hw1_b0, zb,
                                                     hw1_w1, w1c, first_nc * 9216 / 4);
  k_attnpre<<<dim3(2048), dim3(128), 0, stream>>>(enc, fc_w, fc_b, attn_w, psb, peb);
  k_attn<<<dim3(256, 8), dim3(256), 0, stream>>>(enc, psb, peb, v_w, cbuf);
  // w1flat = z @ w1^T + b1 (new 2-blocks/CU GEMM; chunk0 pre-converted in fused kernel)
  for (int c0 = 0; c0 < 9216; c0 += chunk_rows){
    int nc = 9216 - c0; if (nc > chunk_rows) nc = chunk_rows;
    if (c0 > 0)
      k_f32_to_bf16<<<dim3(2048), dim3(256), 0, stream>>>(hw1_w1 + (size_t)c0 * 9216, w1c, nc * 9216 / 4);
    k_gemm288<0><<<dim3(16 * (nc / 288)), dim3(256), 0, stream>>>(zb, w1c, hw1_b1 + c0, w1f + c0,
                                                                  2048, nc, 9216, 9216);
  }
  k_final<<<dim3(2048), dim3(256), 0, stream>>>(states, act, cbuf, w1f,
      hb1_w, hb1_b, hwf_w0, hwf_b0, hwf_w1, hwf_b1, hb2_w0, hb2_b0, hb2_w1, hb2_b1,
      outp);
}

// Round 12
// 742.605 us; speedup vs baseline: 1.0731x; 1.0731x over previous
//
#include <hip/hip_runtime.h>
#include <hip/hip_bf16.h>
#include <stdint.h>

typedef __attribute__((ext_vector_type(4))) float f32x4;
typedef __attribute__((ext_vector_type(8))) short short8v;
typedef __attribute__((ext_vector_type(4))) unsigned short u16x4;

constexpr int kT  = 256;
constexpr int kA  = 160;

__device__ __forceinline__ float bf2f(unsigned short u){
  union { unsigned int u; float f; } c; c.u = ((unsigned int)u) << 16; return c.f;
}
__device__ __forceinline__ unsigned short f2bf(float f){
  union { float f; unsigned int u; } c; c.f = f;
  unsigned int r = (c.u + 0x7FFFu + ((c.u >> 16) & 1u)) >> 16;
  return (unsigned short)r;
}
__device__ __forceinline__ float sigmoid_fast(float x){
  return __builtin_amdgcn_rcpf(1.f + __expf(-x));
}
__device__ __forceinline__ float tanhf_fast(float x){
  float xc = fminf(fmaxf(x, -15.f), 15.f);
  float t = __expf(2.f * xc);
  return (t - 1.f) * __builtin_amdgcn_rcpf(t + 1.f);
}
__device__ __forceinline__ void gload_lds16(const void* g, void* l){
  __builtin_amdgcn_global_load_lds((const __attribute__((address_space(1))) void*)g,
                                   (__attribute__((address_space(3))) void*)l, 16, 0, 0);
}
__device__ __forceinline__ void bar_lgkm(){
  asm volatile("s_waitcnt lgkmcnt(0)" ::: "memory");
  __builtin_amdgcn_s_barrier();
  asm volatile("" ::: "memory");
}
__device__ __forceinline__ void bar_only(){
  asm volatile("" ::: "memory");
  __builtin_amdgcn_s_barrier();
  asm volatile("" ::: "memory");
}

// ---------------- diagnostic fill (f32) ----------------
__global__ __launch_bounds__(256) void k_fill_f32(float* out, int n, float v){
  int i = blockIdx.x * blockDim.x + threadIdx.x;
  if (i < n) out[i] = v;
}

// ---------------- f32 -> bf16 convert ----------------
__global__ __launch_bounds__(256) void k_f32_to_bf16(const float* __restrict__ src,
                                                     unsigned short* __restrict__ dst, int n4){
  int stride = gridDim.x * blockDim.x;
  for (int i = blockIdx.x * blockDim.x + threadIdx.x; i < n4; i += stride){
    f32x4 v = *(const f32x4*)(src + (size_t)i * 4);
    u16x4 o;
    o[0] = f2bf(v[0]); o[1] = f2bf(v[1]); o[2] = f2bf(v[2]); o[3] = f2bf(v[3]);
    *(u16x4*)(dst + (size_t)i * 4) = o;
  }
}

// ---------------- gi = shift(act) @ wih^T + bih ----------------
__global__ __launch_bounds__(384) void k_gi(const float* __restrict__ act,
                                            const float* __restrict__ wih,
                                            const float* __restrict__ bih,
                                            float* __restrict__ gi){
  int blk = blockIdx.x;
  int b = blk >> 5, tg = blk & 31;
  int j = threadIdx.x;
  __shared__ __align__(16) float xh[8][kA];
  for (int idx = j; idx < 8 * kA; idx += 384){
    int u = idx / kA, i = idx - u * kA;
    int t = tg * 8 + u;
    xh[u][i] = (t == 0) ? 0.f : act[((size_t)b * kT + t - 1) * kA + i];
  }
  __syncthreads();
  float acc[8] = {0,0,0,0,0,0,0,0};
  for (int i = 0; i < kA; i += 4){
    f32x4 wv = *(const f32x4*)(wih + (size_t)j * kA + i);
#pragma unroll
    for (int jj = 0; jj < 4; ++jj)
#pragma unroll
      for (int u = 0; u < 8; ++u)
        acc[u] += wv[jj] * xh[u][i + jj];
  }
  float bv = bih[j];
#pragma unroll
  for (int u = 0; u < 8; ++u)
    gi[((size_t)b * kT + tg * 8 + u) * 384 + j] = acc[u] + bv;
}

// ================= r10 GEMM body (512 thr, 128x576) — PROVEN 391us/888TF =================
template<int RELU>
__device__ __forceinline__ void gemm576_body(const unsigned short* __restrict__ A,
                                             const unsigned short* __restrict__ B,
                                             const float* __restrict__ bias,
                                             unsigned short* __restrict__ C,
                                             int M, int Nc, int K, int ldc,
                                             int bid, int nwg, char* smem){
  int nbm = M >> 7;
  int cpx = nwg >> 3;
  int sw  = (bid & 7) * cpx + (bid >> 3);
  int bm = sw % nbm, bn = sw / nbm;
  int arow0 = bm << 7;
  int bcol0 = bn * 576;
  int t = threadIdx.x;
  int l = t & 63, w = t >> 6;
  int wr = w >> 2, wc = w & 3;
  int lr = l & 15, kq = l >> 4;
  int Kb = K * 2;
  int ar = t >> 2, ap = t & 3;
  size_t aoffg = (size_t)ar * Kb + ((ap ^ ((ar >> 1) & 3)) << 4);
  size_t boffg[5];
#pragma unroll
  for (int i = 0; i < 5; ++i){
    int q = i * 512 + t, r = q >> 2, p = q & 3;
    boffg[i] = (size_t)r * Kb + ((p ^ ((r >> 1) & 3)) << 4);
  }
  const char* Ag = (const char*)(A + (size_t)arow0 * K);
  const char* Bg = (const char*)(B + (size_t)bcol0 * K);
  int dA = t * 16;
  int kk16 = (kq ^ ((lr >> 1) & 3)) << 4;
  int aRd = (wr * 64 + lr) * 64 + kk16;
  int bRd = 8192 + (wc * 144 + lr) * 64 + kk16;
  f32x4 acc[4][9] = {};
  int nt = K >> 5;

  auto stage = [&](int kt, int bi){
    size_t kb = (size_t)kt * 64;
    char* Ld = smem + bi * 49152;
    gload_lds16(Ag + aoffg + kb, Ld + dA);
#pragma unroll
    for (int i = 0; i < 5; ++i)
      gload_lds16(Bg + boffg[i] + kb, Ld + 8192 + i * 8192 + dA);
  };

  stage(0, 0);
  stage(1, 1);
  asm volatile("s_waitcnt vmcnt(6)" ::: "memory");
  int cur = 0;
  for (int kt = 0; kt < nt; ++kt){
    bar_only();
    if (kt + 2 < nt){
      int nb = cur + 2; if (nb >= 3) nb -= 3;
      stage(kt + 2, nb);
    }
    const char* Ld = smem + cur * 49152;
    short8v af[4];
#pragma unroll
    for (int m = 0; m < 4; ++m) af[m] = *(const short8v*)(Ld + aRd + m * 1024);
#pragma unroll
    for (int c = 0; c < 3; ++c){
      short8v bf[3];
#pragma unroll
      for (int j = 0; j < 3; ++j) bf[j] = *(const short8v*)(Ld + bRd + (c * 3 + j) * 1024);
      __builtin_amdgcn_s_setprio(1);
#pragma unroll
      for (int m = 0; m < 4; ++m)
#pragma unroll
        for (int j = 0; j < 3; ++j)
          acc[m][c * 3 + j] = __builtin_amdgcn_mfma_f32_16x16x32_bf16(af[m], bf[j], acc[m][c * 3 + j], 0, 0, 0);
      __builtin_amdgcn_s_setprio(0);
    }
    if (kt + 1 < nt){
      if (kt + 2 < nt) asm volatile("s_waitcnt vmcnt(6)" ::: "memory");
      else             asm volatile("s_waitcnt vmcnt(0)" ::: "memory");
    }
    ++cur; if (cur == 3) cur = 0;
  }

#pragma unroll
  for (int m = 0; m < 4; ++m){
    int row = arow0 + wr * 64 + m * 16 + kq * 4;
#pragma unroll
    for (int n = 0; n < 9; ++n){
      int col = bcol0 + wc * 144 + n * 16 + lr;
      float bv = bias[col];
#pragma unroll
      for (int r = 0; r < 4; ++r){
        float v = acc[m][n][r] + bv;
        if (RELU) v = fmaxf(v, 0.f);
        C[(size_t)(row + r) * ldc + col] = f2bf(v);
      }
    }
  }
}

template<int RELU>
__global__ __launch_bounds__(512) void k_gemm576(const unsigned short* __restrict__ A,
                                                 const unsigned short* __restrict__ B,
                                                 const float* __restrict__ bias,
                                                 unsigned short* __restrict__ C,
                                                 int M, int Nc, int K, int ldc){
  __shared__ __align__(16) char smem[147456];
  gemm576_body<RELU>(A, B, bias, C, M, Nc, K, ldc, blockIdx.x, gridDim.x, smem);
}

// ---------------- fused: blocks 0-7 GRU; 8-263 GEMM1; 264+ convert (now 1784 blocks) ----
__global__ __launch_bounds__(512) void k_gru_g1_conv(const float* __restrict__ gi,
                                                     const float* __restrict__ whh,
                                                     const float* __restrict__ bhh,
                                                     float* __restrict__ enc,
                                                     const unsigned short* __restrict__ stb,
                                                     const unsigned short* __restrict__ w0b,
                                                     const float* __restrict__ hb0,
                                                     unsigned short* __restrict__ zb,
                                                     const float* __restrict__ csrc,
                                                     unsigned short* __restrict__ cdst,
                                                     int n4){
  __shared__ __align__(16) char smem[147456];
  int blk = blockIdx.x;
  if (blk >= 264){
    int stride = (gridDim.x - 264) * 512;
    for (int i = (blk - 264) * 512 + threadIdx.x; i < n4; i += stride){
      f32x4 v = *(const f32x4*)(csrc + (size_t)i * 4);
      u16x4 o;
      o[0] = f2bf(v[0]); o[1] = f2bf(v[1]); o[2] = f2bf(v[2]); o[3] = f2bf(v[3]);
      *(u16x4*)(cdst + (size_t)i * 4) = o;
    }
    return;
  }
  if (blk >= 8){
    gemm576_body<1>(stb, w0b, hb0, zb, 2048, 9216, 256, 9216, blk - 8, 256, smem);
    return;
  }
  // ---- GRU ----
  float* h_lds = (float*)smem;
  float (*red)[128] = (float(*)[128])(smem + 512);
  int b = blk;
  int tid = threadIdx.x;
  int e = tid & 127, s = tid >> 7;
  float W0[32], W1[32], W2[32];
#pragma unroll
  for (int k = 0; k < 32; ++k){
    W0[k] = whh[(size_t)(0 * 128 + e) * 128 + s * 32 + k];
    W1[k] = whh[(size_t)(1 * 128 + e) * 128 + s * 32 + k];
    W2[k] = whh[(size_t)(2 * 128 + e) * 128 + s * 32 + k];
  }
  if (tid < 128) h_lds[tid] = 0.f;
  float bh0 = 0.f, bh1 = 0.f, bh2 = 0.f;
  if (tid < 128){ bh0 = bhh[e]; bh1 = bhh[128 + e]; bh2 = bhh[256 + e]; }
  const float* gib = gi + (size_t)b * kT * 384;
  float* encb = enc + (size_t)b * kT * 128;
  float gir = 0.f, giz = 0.f, gin = 0.f;
  if (tid < 128){ gir = gib[e]; giz = gib[128 + e]; gin = gib[256 + e]; }
  bar_lgkm();
  for (int t = 0; t < kT; ++t){
    float p0 = 0.f, p1 = 0.f, p2 = 0.f;
#pragma unroll
    for (int k4 = 0; k4 < 8; ++k4){
      f32x4 hv = *(const f32x4*)(h_lds + s * 32 + k4 * 4);
#pragma unroll
      for (int jj = 0; jj < 4; ++jj){
        p0 += W0[k4 * 4 + jj] * hv[jj];
        p1 += W1[k4 * 4 + jj] * hv[jj];
        p2 += W2[k4 * 4 + jj] * hv[jj];
      }
    }
    float nir = 0.f, niz = 0.f, nin = 0.f;
    if (t + 1 < kT && tid < 128){
      const float* gn = gib + (size_t)(t + 1) * 384;
      nir = gn[e]; niz = gn[128 + e]; nin = gn[256 + e];
    }
    red[s * 3 + 0][e] = p0; red[s * 3 + 1][e] = p1; red[s * 3 + 2][e] = p2;
    bar_lgkm();
    if (tid < 128){
      float ghr = red[0][e] + red[3][e] + red[6][e] + red[9][e]  + bh0;
      float ghz = red[1][e] + red[4][e] + red[7][e] + red[10][e] + bh1;
      float ghn = red[2][e] + red[5][e] + red[8][e] + red[11][e] + bh2;
      float r = sigmoid_fast(gir + ghr);
      float z = sigmoid_fast(giz + ghz);
      float n = tanhf_fast(gin + r * ghn);
      float hnew = (1.f - z) * n + z * h_lds[e];
      h_lds[e] = hnew;
      encb[t * 128 + e] = hnew;
    }
    bar_lgkm();
    gir = nir; giz = niz; gin = nin;
  }
}

// ---------------- s0/ps/pe ----------------
__global__ __launch_bounds__(128) void k_attnpre(const float* __restrict__ enc,
                                                 const float* __restrict__ fc_w,
                                                 const float* __restrict__ fc_b,
                                                 const float* __restrict__ attn_w,
                                                 float* __restrict__ ps,
                                                 float* __restrict__ pe){
  int bt = blockIdx.x, o = threadIdx.x;
  __shared__ __align__(16) float ench[128], s0h[128];
  ench[o] = enc[(size_t)bt * 128 + o];
  __syncthreads();
  float a0 = fc_b[o], a1 = 0.f;
  for (int i = 0; i < 128; i += 4){
    f32x4 wv = *(const f32x4*)(fc_w + (size_t)o * 128 + i);
    f32x4 we = *(const f32x4*)(attn_w + (size_t)o * 256 + 128 + i);
    f32x4 ev = *(const f32x4*)(ench + i);
#pragma unroll
    for (int jj = 0; jj < 4; ++jj){ a0 += wv[jj] * ev[jj]; a1 += we[jj] * ev[jj]; }
  }
  s0h[o] = tanhf_fast(a0);
  pe[(size_t)bt * 128 + o] = a1;
  __syncthreads();
  float a2 = 0.f;
  for (int i = 0; i < 128; i += 4){
    f32x4 ws = *(const f32x4*)(attn_w + (size_t)o * 256 + i);
    f32x4 sv = *(const f32x4*)(s0h + i);
#pragma unroll
    for (int jj = 0; jj < 4; ++jj) a2 += ws[jj] * sv[jj];
  }
  ps[(size_t)bt * 128 + o] = a2;
}

// ---------------- causal additive attention ----------------
__global__ __launch_bounds__(256) void k_attn(const float* __restrict__ enc,
                                              const float* __restrict__ ps,
                                              const float* __restrict__ pe,
                                              const float* __restrict__ v_w,
                                              float* __restrict__ cbuf){
  int q = blockIdx.x, b = blockIdx.y;
  int tid = threadIdx.x;
  __shared__ __align__(16) float psh[128], vwh[128];
  __shared__ __align__(16) float sch[256];
  __shared__ __align__(16) float rr[256];
  __shared__ float mxs, dns;
  if (tid < 128){
    psh[tid] = ps[((size_t)b * kT + q) * 128 + tid];
    vwh[tid] = v_w[tid];
  }
  __syncthreads();
  int nk = q + 1;
  for (int k = tid; k < nk; k += 256){
    const float* per = pe + ((size_t)b * kT + k) * 128;
    float sc = 0.f;
    for (int d = 0; d < 128; d += 4){
      f32x4 pv = *(const f32x4*)(per + d);
      f32x4 qv = *(const f32x4*)(psh + d);
      sc += vwh[d + 0] * tanhf_fast(qv[0] + pv[0]);
      sc += vwh[d + 1] * tanhf_fast(qv[1] + pv[1]);
      sc += vwh[d + 2] * tanhf_fast(qv[2] + pv[2]);
      sc += vwh[d + 3] * tanhf_fast(qv[3] + pv[3]);
    }
    sch[k] = sc;
  }
  __syncthreads();
  float lm = -3.0e38f;
  for (int k = tid; k < nk; k += 256) lm = fmaxf(lm, sch[k]);
  rr[tid] = lm; __syncthreads();
  for (int off = 128; off > 0; off >>= 1){
    if (tid < off) rr[tid] = fmaxf(rr[tid], rr[tid + off]);
    __syncthreads();
  }
  if (tid == 0) mxs = rr[0];
  __syncthreads();
  float mxv = mxs;
  float lsum = 0.f;
  for (int k = tid; k < nk; k += 256){
    float p = __expf(sch[k] - mxv);
    sch[k] = p; lsum += p;
  }
  __syncthreads();
  rr[tid] = lsum; __syncthreads();
  for (int off = 128; off > 0; off >>= 1){
    if (tid < off) rr[tid] += rr[tid + off];
    __syncthreads();
  }
  if (tid == 0) dns = __builtin_amdgcn_rcpf(rr[0]);
  __syncthreads();
  float rd = dns;
  int d = tid & 127, half = tid >> 7;
  float acc = 0.f;
  for (int k = half; k < nk; k += 2)
    acc += sch[k] * enc[((size_t)b * kT + k) * 128 + d];
  rr[tid] = acc; __syncthreads();
  if (half == 0)
    cbuf[((size_t)b * kT + q) * 128 + d] = (acc + rr[d + 128]) * rd;
}

// ---------------- final: heads + per-row 288x32 contraction -> q (f32 out) ----------------
__global__ __launch_bounds__(256) void k_final(const float* __restrict__ states,
                                               const float* __restrict__ act,
                                               const float* __restrict__ cbuf,
                                               const unsigned short* __restrict__ w1f, // bf16
                                               const float* __restrict__ hb1_w, const float* __restrict__ hb1_b,
                                               const float* __restrict__ hwf_w0, const float* __restrict__ hwf_b0,
                                               const float* __restrict__ hwf_w1, const float* __restrict__ hwf_b1,
                                               const float* __restrict__ hb2_w0, const float* __restrict__ hb2_b0,
                                               const float* __restrict__ hb2_w1, const float* __restrict__ hb2_b1,
                                               float* __restrict__ out){
  int bt = blockIdx.x, tid = threadIdx.x;
  __shared__ __align__(16) float sth[256], inph[288], red[256];
  __shared__ __align__(16) float t1h[32], t2h[32], b1h[32], wfh[32], hvals[32];
  __shared__ float b2s;
  sth[tid] = states[(size_t)bt * 256 + tid];
  if (tid < 160) inph[tid] = act[(size_t)bt * 160 + tid];
  if (tid < 128) inph[160 + tid] = cbuf[(size_t)bt * 128 + tid];
  __syncthreads();
  int o = tid & 31, s = tid >> 5;
  float p1 = 0.f, p2 = 0.f, p3 = 0.f;
  for (int k = s * 32; k < s * 32 + 32; k += 4){
    f32x4 sv  = *(const f32x4*)(sth + k);
    f32x4 w1v = *(const f32x4*)(hwf_w0 + (size_t)o * 256 + k);
    f32x4 w2v = *(const f32x4*)(hb2_w0 + (size_t)o * 256 + k);
    f32x4 w3v = *(const f32x4*)(hb1_w  + (size_t)o * 256 + k);
#pragma unroll
    for (int jj = 0; jj < 4; ++jj){
      p1 += w1v[jj] * sv[jj]; p2 += w2v[jj] * sv[jj]; p3 += w3v[jj] * sv[jj];
    }
  }
  red[tid] = p1; __syncthreads();
  if (tid < 32){
    float a = hwf_b0[tid];
#pragma unroll
    for (int s8 = 0; s8 < 8; ++s8) a += red[s8 * 32 + tid];
    t1h[tid] = fmaxf(a, 0.f);
  }
  __syncthreads();
  red[tid] = p2; __syncthreads();
  if (tid < 32){
    float a = hb2_b0[tid];
#pragma unroll
    for (int s8 = 0; s8 < 8; ++s8) a += red[s8 * 32 + tid];
    t2h[tid] = fmaxf(a, 0.f);
  }
  __syncthreads();
  red[tid] = p3; __syncthreads();
  if (tid < 32){
    float a = hb1_b[tid];
#pragma unroll
    for (int s8 = 0; s8 < 8; ++s8) a += red[s8 * 32 + tid];
    b1h[tid] = a;
  }
  __syncthreads();
  if (tid < 32){
    float a = hwf_b1[tid];
#pragma unroll
    for (int j = 0; j < 32; ++j) a += hwf_w1[(size_t)tid * 32 + j] * t1h[j];
    wfh[tid] = a;
  }
  if (tid == 64){
    float a = hb2_b1[0];
#pragma unroll
    for (int j = 0; j < 32; ++j) a += hb2_w1[j] * t2h[j];
    b2s = a;
  }
  __syncthreads();
  float ph = 0.f;
  const unsigned short* wrow = w1f + (size_t)bt * 9216;
  for (int i = s * 36; i < s * 36 + 36; ++i)
    ph += inph[i] * bf2f(wrow[i * 32 + o]);
  red[tid] = ph; __syncthreads();
  if (tid < 32){
    float a = b1h[tid];
#pragma unroll
    for (int s8 = 0; s8 < 8; ++s8) a += red[s8 * 32 + tid];
    hvals[tid] = fmaxf(a, 0.f) * wfh[tid];
  }
  __syncthreads();
  if (tid == 0){
    float q = b2s;
#pragma unroll
    for (int j = 0; j < 32; ++j) q += hvals[j];
    out[bt] = q;
  }
}

extern "C" void kernel_launch(void* const* d_in, const int* in_sizes, int n_in,
                              void* d_out, int out_size, void* d_ws, size_t ws_size,
                              hipStream_t stream){
  float* outp = (float*)d_out;

  bool ok = (n_in == 24) && out_size == 2048 &&
            in_sizes[0] == 327680 && in_sizes[1] == 524288 &&
            in_sizes[2] == 61440  && in_sizes[3] == 49152 &&
            in_sizes[10] == 2359296 && in_sizes[12] == 84934656;
  if (!ok){
    k_fill_f32<<<dim3(8), dim3(256), 0, stream>>>(outp, 2048, 1.0e6f);
    return;
  }

  const float* act    = (const float*)d_in[0];
  const float* states = (const float*)d_in[1];
  const float* wih    = (const float*)d_in[2];
  const float* whh    = (const float*)d_in[3];
  const float* bih    = (const float*)d_in[4];
  const float* bhh    = (const float*)d_in[5];
  const float* fc_w   = (const float*)d_in[6];
  const float* fc_b   = (const float*)d_in[7];
  const float* attn_w = (const float*)d_in[8];
  const float* v_w    = (const float*)d_in[9];
  const float* hw1_w0 = (const float*)d_in[10];
  const float* hw1_b0 = (const float*)d_in[11];
  const float* hw1_w1 = (const float*)d_in[12];
  const float* hw1_b1 = (const float*)d_in[13];
  const float* hwf_w0 = (const float*)d_in[14];
  const float* hwf_b0 = (const float*)d_in[15];
  const float* hwf_w1 = (const float*)d_in[16];
  const float* hwf_b1 = (const float*)d_in[17];
  const float* hb1_w  = (const float*)d_in[18];
  const float* hb1_b  = (const float*)d_in[19];
  const float* hb2_w0 = (const float*)d_in[20];
  const float* hb2_b0 = (const float*)d_in[21];
  const float* hb2_w1 = (const float*)d_in[22];
  const float* hb2_b1 = (const float*)d_in[23];

  char* ws = (char*)d_ws;
  size_t off = 0;
  auto alloc = [&](size_t bytes)->void*{
    void* p = ws + off; off += (bytes + 255) & ~(size_t)255; return p;
  };
  unsigned short* zb  = (unsigned short*)alloc((size_t)2048 * 9216 * 2);
  unsigned short* w1f = (unsigned short*)alloc((size_t)2048 * 9216 * 2);
  unsigned short* w0b = (unsigned short*)alloc((size_t)9216 * 256 * 2);
  unsigned short* stb = (unsigned short*)alloc((size_t)2048 * 256 * 2);
  float* gi   = (float*)alloc((size_t)2048 * 384 * 4);
  float* enc  = (float*)alloc((size_t)2048 * 128 * 4);
  float* psb  = (float*)alloc((size_t)2048 * 128 * 4);
  float* peb  = (float*)alloc((size_t)2048 * 128 * 4);
  float* cbuf = (float*)alloc((size_t)2048 * 128 * 4);
  size_t floor_bytes = off;
  const size_t row_bytes = (size_t)9216 * 2;
  const size_t slack = (size_t)2 << 20;               // B-stage overrun slack
  if (ws_size < floor_bytes + 576 * row_bytes + slack){
    k_fill_f32<<<dim3(8), dim3(256), 0, stream>>>(outp, 2048, (float)(ws_size >> 20));
    return;
  }
  size_t avail = ws_size - floor_bytes - slack;
  int chunk_rows = (int)(((avail / row_bytes) / 576) * 576);
  if (chunk_rows > 9216) chunk_rows = 9216;
  unsigned short* w1c = (unsigned short*)(ws + floor_bytes);
  int first_nc = chunk_rows;

  // ---- pipeline ----
  k_f32_to_bf16<<<dim3(1024), dim3(256), 0, stream>>>(hw1_w0, w0b, 9216 * 256 / 4);
  k_f32_to_bf16<<<dim3(256),  dim3(256), 0, stream>>>(states, stb, 2048 * 256 / 4);
  k_gi<<<dim3(256), dim3(384), 0, stream>>>(act, wih, bih, gi);
  // GRU (0-7) || GEMM1 z=relu(st@w0^T+b0) (8-263) || convert w1 chunk0 (264..2047)
  k_gru_g1_conv<<<dim3(2048), dim3(512), 0, stream>>>(gi, whh, bhh, enc,
                                                      stb, w0b, hw1_b0, zb,
                                                      hw1_w1, w1c, first_nc * 9216 / 4);
  k_attnpre<<<dim3(2048), dim3(128), 0, stream>>>(enc, fc_w, fc_b, attn_w, psb, peb);
  k_attn<<<dim3(256, 8), dim3(256), 0, stream>>>(enc, psb, peb, v_w, cbuf);
  // w1flat = z @ w1^T + b1 (r10-proven GEMM; chunk0 pre-converted in fused kernel)
  for (int c0 = 0; c0 < 9216; c0 += chunk_rows){
    int nc = 9216 - c0; if (nc > chunk_rows) nc = chunk_rows;
    if (c0 > 0)
      k_f32_to_bf16<<<dim3(2048), dim3(256), 0, stream>>>(hw1_w1 + (size_t)c0 * 9216, w1c, nc * 9216 / 4);
    k_gemm576<0><<<dim3(16 * (nc / 576)), dim3(512), 0, stream>>>(zb, w1c, hw1_b1 + c0, w1f + c0,
                                                                  2048, nc, 9216, 9216);
  }
  k_final<<<dim3(2048), dim3(256), 0, stream>>>(states, act, cbuf, w1f,
      hb1_w, hb1_b, hwf_w0, hwf_b0, hwf_w1, hwf_b1, hb2_w0, hb2_b0, hb2_w1, hb2_b1,
      outp);
}